// Round 1
// baseline (545.065 us; speedup 1.0000x reference)
//
#include <hip/hip_runtime.h>

// RecurrentDiscriminator: B=65536 independent 64-step recurrences.
// 1 thread = 1 batch element; weights read via wave-uniform global loads
// (compiler -> s_load / SGPR operands); obs streamed as float4 with
// 1-step-ahead register prefetch. fp32 throughout.

#define NB   65536
#define NS   64
#define OBSD 20
#define NH   10

__device__ __forceinline__ float ftanh(float x) {
    // tanh(x) = 1 - 2/(exp(2x)+1); exact saturation at +/-inf, ~1e-6 abs err
    float e = __expf(2.0f * x);
    return 1.0f - __fdividef(2.0f, e + 1.0f);
}

__global__ __launch_bounds__(256, 1)
void rd_fwd(const float* __restrict__ states, const float* __restrict__ actions,
            const float* __restrict__ W1, const float* __restrict__ b1,
            const float* __restrict__ W2, const float* __restrict__ b2,
            const float* __restrict__ W3, const float* __restrict__ b3,
            const float* __restrict__ Wg1, const float* __restrict__ bg1,
            const float* __restrict__ Wg2, const float* __restrict__ bg2,
            float* __restrict__ out)
{
    const int b = blockIdx.x * blockDim.x + threadIdx.x;
    const float* __restrict__ row = states + (size_t)b * (NS * OBSD);
    const float a0 = actions[2 * b];
    const float a1 = actions[2 * b + 1];

    float st[NH];
#pragma unroll
    for (int o = 0; o < NH; ++o) st[o] = 0.0f;

    float cur[OBSD], nxt[OBSD];
    // prefetch step 0 (row offsets are 16B-aligned: 80B per step)
#pragma unroll
    for (int q = 0; q < 5; ++q) {
        float4 v = *(const float4*)(row + 4 * q);
        cur[4*q+0] = v.x; cur[4*q+1] = v.y; cur[4*q+2] = v.z; cur[4*q+3] = v.w;
    }

#pragma unroll 1
    for (int s = 0; s < NS; ++s) {
        // prefetch next step's obs while computing this step
        if (s + 1 < NS) {
#pragma unroll
            for (int q = 0; q < 5; ++q) {
                float4 v = *(const float4*)(row + (s + 1) * OBSD + 4 * q);
                nxt[4*q+0] = v.x; nxt[4*q+1] = v.y; nxt[4*q+2] = v.z; nxt[4*q+3] = v.w;
            }
        }

        // ---- layer 1: h1 = tanh([st, obs, act] @ W1 + b1) ----
        float acc[NH];
#pragma unroll
        for (int o = 0; o < NH; ++o) acc[o] = b1[o];
#pragma unroll
        for (int i = 0; i < NH; ++i) {
            const float xi = st[i];
#pragma unroll
            for (int o = 0; o < NH; ++o) acc[o] = fmaf(xi, W1[i * NH + o], acc[o]);
        }
#pragma unroll
        for (int i = 0; i < OBSD; ++i) {
            const float xi = cur[i];
#pragma unroll
            for (int o = 0; o < NH; ++o) acc[o] = fmaf(xi, W1[(NH + i) * NH + o], acc[o]);
        }
#pragma unroll
        for (int o = 0; o < NH; ++o) acc[o] = fmaf(a0, W1[30 * NH + o], acc[o]);
#pragma unroll
        for (int o = 0; o < NH; ++o) acc[o] = fmaf(a1, W1[31 * NH + o], acc[o]);

        float h1[NH];
#pragma unroll
        for (int o = 0; o < NH; ++o) h1[o] = ftanh(acc[o]);

        // ---- layer 2: h2 = tanh(h1 @ W2 + b2) ----
        float acc2[NH];
#pragma unroll
        for (int o = 0; o < NH; ++o) acc2[o] = b2[o];
#pragma unroll
        for (int i = 0; i < NH; ++i) {
            const float xi = h1[i];
#pragma unroll
            for (int o = 0; o < NH; ++o) acc2[o] = fmaf(xi, W2[i * NH + o], acc2[o]);
        }
        float h2[NH];
#pragma unroll
        for (int o = 0; o < NH; ++o) h2[o] = ftanh(acc2[o]);

        // ---- state update: st += h2 @ W3 + b3 ----
#pragma unroll
        for (int o = 0; o < NH; ++o) st[o] += b3[o];
#pragma unroll
        for (int i = 0; i < NH; ++i) {
            const float xi = h2[i];
#pragma unroll
            for (int o = 0; o < NH; ++o) st[o] = fmaf(xi, W3[i * NH + o], st[o]);
        }

        // rotate prefetch buffer
#pragma unroll
        for (int i = 0; i < OBSD; ++i) cur[i] = nxt[i];
    }

    // ---- head: out = tanh(st @ Wg1 + bg1) @ Wg2 + bg2 ----
    float g[NH];
#pragma unroll
    for (int o = 0; o < NH; ++o) {
        float acc = bg1[o];
#pragma unroll
        for (int i = 0; i < NH; ++i) acc = fmaf(st[i], Wg1[i * NH + o], acc);
        g[o] = ftanh(acc);
    }
    float r = bg2[0];
#pragma unroll
    for (int o = 0; o < NH; ++o) r = fmaf(g[o], Wg2[o], r);
    out[b] = r;
}

extern "C" void kernel_launch(void* const* d_in, const int* in_sizes, int n_in,
                              void* d_out, int out_size, void* d_ws, size_t ws_size,
                              hipStream_t stream) {
    const float* states  = (const float*)d_in[0];
    const float* actions = (const float*)d_in[1];
    const float* W1  = (const float*)d_in[2];
    const float* b1  = (const float*)d_in[3];
    const float* W2  = (const float*)d_in[4];
    const float* b2  = (const float*)d_in[5];
    const float* W3  = (const float*)d_in[6];
    const float* b3  = (const float*)d_in[7];
    const float* Wg1 = (const float*)d_in[8];
    const float* bg1 = (const float*)d_in[9];
    const float* Wg2 = (const float*)d_in[10];
    const float* bg2 = (const float*)d_in[11];
    float* out = (float*)d_out;

    rd_fwd<<<NB / 256, 256, 0, stream>>>(states, actions, W1, b1, W2, b2,
                                         W3, b3, Wg1, bg1, Wg2, bg2, out);
}

// Round 2
// 314.064 us; speedup vs baseline: 1.7355x; 1.7355x over previous
//
#include <hip/hip_runtime.h>

// RecurrentDiscriminator: B=65536 independent 64-step recurrences, 1 thread/element.
// Round 2: force W1+biases resident in VGPRs (asm keep-alive pins them);
// W2/W3 time-share one 100-reg buffer streamed from L1 each step with the
// base pointers laundered through asm to defeat LICM; obs prefetched into
// the same 20 regs right after layer1 consumes them.

#define NB   65536
#define NS   64
#define OBSD 20
#define NH   10
#define IND  32

// Pin a value into a VGPR and make it opaque (no remat/sink of its producer).
#define KEEP(x) asm volatile("" : "+v"(x))

__device__ __forceinline__ float ftanh(float x) {
    // tanh(x) = 1 - 2/(exp(2x)+1); exp(2x) = 2^(2*log2e*x)
    float e = __builtin_amdgcn_exp2f(x * 2.88539008177793f);
    float r = __builtin_amdgcn_rcpf(1.0f + e);
    return fmaf(-2.0f, r, 1.0f);   // exact saturation at +/-inf
}

__global__ __launch_bounds__(256, 1)
void rd_fwd(const float* __restrict__ states, const float* __restrict__ actions,
            const float* __restrict__ W1, const float* __restrict__ b1,
            const float* __restrict__ W2, const float* __restrict__ b2,
            const float* __restrict__ W3, const float* __restrict__ b3,
            const float* __restrict__ Wg1, const float* __restrict__ bg1,
            const float* __restrict__ Wg2, const float* __restrict__ bg2,
            float* __restrict__ out)
{
    const int b = blockIdx.x * blockDim.x + threadIdx.x;
    const float* __restrict__ row = states + (size_t)b * (NS * OBSD);
    const float a0 = actions[2 * b];
    const float a1 = actions[2 * b + 1];

    // ---- hoist W1 (320 floats) into VGPRs, pinned ----
    float w1[IND * NH];
#pragma unroll
    for (int i = 0; i < IND * NH; i += 4) {
        float4 v = *(const float4*)(W1 + i);
        w1[i] = v.x; w1[i+1] = v.y; w1[i+2] = v.z; w1[i+3] = v.w;
    }
#pragma unroll
    for (int i = 0; i < IND * NH; ++i) KEEP(w1[i]);

    // biases resident (30 regs)
    float b1r[NH], b2r[NH], b3r[NH];
#pragma unroll
    for (int o = 0; o < NH; ++o) { b1r[o] = b1[o]; b2r[o] = b2[o]; b3r[o] = b3[o]; }

    float st[NH];
#pragma unroll
    for (int o = 0; o < NH; ++o) st[o] = 0.0f;

    // obs for step 0
    float cur[OBSD];
#pragma unroll
    for (int q = 0; q < 5; ++q) {
        float4 v = *(const float4*)(row + 4 * q);
        cur[4*q] = v.x; cur[4*q+1] = v.y; cur[4*q+2] = v.z; cur[4*q+3] = v.w;
    }

    // W2/W3 time-shared stream buffer (100 regs). Launder base pointers so
    // the per-step loads can't be LICM-hoisted (which would double the buffer).
    const float* w2p = W2;
    const float* w3p = W3;
    float wbuf[NH * NH];

#pragma unroll 1
    for (int s = 0; s < NS; ++s) {
        // ---- issue W2 stream early (L1-resident; consumed ~800 cyc later) ----
        asm volatile("" : "+s"(w2p));
#pragma unroll
        for (int i = 0; i < NH * NH; i += 4) {
            float4 v = *(const float4*)(w2p + i);
            wbuf[i] = v.x; wbuf[i+1] = v.y; wbuf[i+2] = v.z; wbuf[i+3] = v.w;
        }

        // ---- layer 1: acc = [st, obs, act] @ W1 + b1 ----
        float acc[NH];
#pragma unroll
        for (int o = 0; o < NH; ++o) acc[o] = b1r[o];
#pragma unroll
        for (int i = 0; i < NH; ++i) {
            const float xi = st[i];
#pragma unroll
            for (int o = 0; o < NH; ++o) acc[o] = fmaf(xi, w1[i * NH + o], acc[o]);
        }
#pragma unroll
        for (int i = 0; i < OBSD; ++i) {
            const float xi = cur[i];
#pragma unroll
            for (int o = 0; o < NH; ++o) acc[o] = fmaf(xi, w1[(NH + i) * NH + o], acc[o]);
        }

        // ---- obs consumed: prefetch next step into the SAME 20 regs ----
        {
            const int sn = (s < NS - 1) ? (s + 1) : s;
            const float* pf = row + sn * OBSD;
#pragma unroll
            for (int q = 0; q < 5; ++q) {
                float4 v = *(const float4*)(pf + 4 * q);
                cur[4*q] = v.x; cur[4*q+1] = v.y; cur[4*q+2] = v.z; cur[4*q+3] = v.w;
            }
        }

#pragma unroll
        for (int o = 0; o < NH; ++o) acc[o] = fmaf(a0, w1[30 * NH + o], acc[o]);
#pragma unroll
        for (int o = 0; o < NH; ++o) acc[o] = fmaf(a1, w1[31 * NH + o], acc[o]);
#pragma unroll
        for (int o = 0; o < NH; ++o) acc[o] = ftanh(acc[o]);   // h1 in place

        // ---- layer 2: acc2 = h1 @ W2 + b2 ----
        float acc2[NH];
#pragma unroll
        for (int o = 0; o < NH; ++o) acc2[o] = b2r[o];
#pragma unroll
        for (int i = 0; i < NH; ++i) {
            const float xi = acc[i];
#pragma unroll
            for (int o = 0; o < NH; ++o) acc2[o] = fmaf(xi, wbuf[i * NH + o], acc2[o]);
        }

        // ---- W2 consumed: stream W3 into the same buffer ----
        asm volatile("" : "+s"(w3p));
#pragma unroll
        for (int i = 0; i < NH * NH; i += 4) {
            float4 v = *(const float4*)(w3p + i);
            wbuf[i] = v.x; wbuf[i+1] = v.y; wbuf[i+2] = v.z; wbuf[i+3] = v.w;
        }

#pragma unroll
        for (int o = 0; o < NH; ++o) acc2[o] = ftanh(acc2[o]);  // h2 in place

        // ---- layer 3: st += h2 @ W3 + b3 ----
#pragma unroll
        for (int o = 0; o < NH; ++o) st[o] += b3r[o];
#pragma unroll
        for (int i = 0; i < NH; ++i) {
            const float xi = acc2[i];
#pragma unroll
            for (int o = 0; o < NH; ++o) st[o] = fmaf(xi, wbuf[i * NH + o], st[o]);
        }
    }

    // ---- head: out = tanh(st @ Wg1 + bg1) @ Wg2 + bg2 ----
    float g[NH];
#pragma unroll
    for (int o = 0; o < NH; ++o) {
        float a = bg1[o];
#pragma unroll
        for (int i = 0; i < NH; ++i) a = fmaf(st[i], Wg1[i * NH + o], a);
        g[o] = ftanh(a);
    }
    float r = bg2[0];
#pragma unroll
    for (int o = 0; o < NH; ++o) r = fmaf(g[o], Wg2[o], r);
    out[b] = r;
}

extern "C" void kernel_launch(void* const* d_in, const int* in_sizes, int n_in,
                              void* d_out, int out_size, void* d_ws, size_t ws_size,
                              hipStream_t stream) {
    const float* states  = (const float*)d_in[0];
    const float* actions = (const float*)d_in[1];
    const float* W1  = (const float*)d_in[2];
    const float* b1  = (const float*)d_in[3];
    const float* W2  = (const float*)d_in[4];
    const float* b2  = (const float*)d_in[5];
    const float* W3  = (const float*)d_in[6];
    const float* b3  = (const float*)d_in[7];
    const float* Wg1 = (const float*)d_in[8];
    const float* bg1 = (const float*)d_in[9];
    const float* Wg2 = (const float*)d_in[10];
    const float* bg2 = (const float*)d_in[11];
    float* out = (float*)d_out;

    rd_fwd<<<NB / 256, 256, 0, stream>>>(states, actions, W1, b1, W2, b2,
                                         W3, b3, Wg1, bg1, Wg2, bg2, out);
}

// Round 3
// 203.824 us; speedup vs baseline: 2.6742x; 1.5409x over previous
//
#include <hip/hip_runtime.h>

// RecurrentDiscriminator round 3.
// - W1 packed f16x2, resident in 160 arch VGPRs, consumed by v_dot2_f32_f16.
// - W2/W3 re-read EVERY step via laundered SGPR pointers -> s_load (scalar
//   pipe broadcast), used directly as the SGPR operand of v_fmac_f32.
//   No wave-redundant vector-memory traffic for weights.
// - Layers 2/3 + head + state accumulation in full fp32.
// - Obs prefetched 1 step ahead as raw float4, packed to f16x2 at step top.

#define NB   65536
#define NS   64
#define OBSD 20
#define NH   10

typedef _Float16 f16x2 __attribute__((ext_vector_type(2)));

#define KEEP(x) asm volatile("" : "+v"(x))

__device__ __forceinline__ float ftanh(float x) {
    // tanh(x) = 1 - 2/(exp(2x)+1); exact saturation at +/-inf
    float e = __builtin_amdgcn_exp2f(x * 2.885390081777927f);  // 2*log2(e)
    float r = __builtin_amdgcn_rcpf(1.0f + e);
    return fmaf(-2.0f, r, 1.0f);
}

__device__ __forceinline__ f16x2 pack2(float a, float b) {
    f16x2 p; p.x = (_Float16)a; p.y = (_Float16)b; return p;  // RNE cvt
}

#if __has_builtin(__builtin_amdgcn_fdot2)
__device__ __forceinline__ float dot2(f16x2 a, f16x2 b, float c) {
    return __builtin_amdgcn_fdot2(a, b, c, false);
}
#else
__device__ __forceinline__ float dot2(f16x2 a, f16x2 b, float c) {
    return fmaf((float)a[0], (float)b[0], fmaf((float)a[1], (float)b[1], c));
}
#endif

__global__ __launch_bounds__(256, 1)
void rd_fwd(const float* __restrict__ states, const float* __restrict__ actions,
            const float* __restrict__ W1, const float* __restrict__ b1,
            const float* __restrict__ W2, const float* __restrict__ b2,
            const float* __restrict__ W3, const float* __restrict__ b3,
            const float* __restrict__ Wg1, const float* __restrict__ bg1,
            const float* __restrict__ Wg2, const float* __restrict__ bg2,
            float* __restrict__ out)
{
    const int b = blockIdx.x * blockDim.x + threadIdx.x;
    const float* __restrict__ row = states + (size_t)b * (NS * OBSD);
    const f16x2 actp = pack2(actions[2 * b], actions[2 * b + 1]);

    // ---- one-time: pack W1 (uniform s_loads) into 160 resident f16x2 ----
    f16x2 w1p[16 * NH];
#pragma unroll
    for (int i2 = 0; i2 < 16; ++i2)
#pragma unroll
        for (int o = 0; o < NH; ++o)
            w1p[i2 * NH + o] = pack2(W1[(2 * i2) * NH + o], W1[(2 * i2 + 1) * NH + o]);
#pragma unroll
    for (int i = 0; i < 16 * NH; ++i) KEEP(w1p[i]);

    // biases: uniform -> SGPR-resident
    float b1r[NH], b2r[NH], b3r[NH];
#pragma unroll
    for (int o = 0; o < NH; ++o) { b1r[o] = b1[o]; b2r[o] = b2[o]; b3r[o] = b3[o]; }

    float st[NH];
#pragma unroll
    for (int o = 0; o < NH; ++o) st[o] = 0.0f;

    // obs prefetch registers (raw f32; packed at top of consuming step)
    float4 nxt0 = *(const float4*)(row + 0);
    float4 nxt1 = *(const float4*)(row + 4);
    float4 nxt2 = *(const float4*)(row + 8);
    float4 nxt3 = *(const float4*)(row + 12);
    float4 nxt4 = *(const float4*)(row + 16);

#pragma unroll 1
    for (int s = 0; s < NS; ++s) {
        // laundered uniform pointers -> per-step s_load on scalar pipe
        const float* w2l = W2; asm volatile("" : "+s"(w2l));
        const float* w3l = W3; asm volatile("" : "+s"(w3l));

        f16x2 obsP[10];
        obsP[0] = pack2(nxt0.x, nxt0.y); obsP[1] = pack2(nxt0.z, nxt0.w);
        obsP[2] = pack2(nxt1.x, nxt1.y); obsP[3] = pack2(nxt1.z, nxt1.w);
        obsP[4] = pack2(nxt2.x, nxt2.y); obsP[5] = pack2(nxt2.z, nxt2.w);
        obsP[6] = pack2(nxt3.x, nxt3.y); obsP[7] = pack2(nxt3.z, nxt3.w);
        obsP[8] = pack2(nxt4.x, nxt4.y); obsP[9] = pack2(nxt4.z, nxt4.w);

        f16x2 stp[5];
#pragma unroll
        for (int p = 0; p < 5; ++p) stp[p] = pack2(st[2 * p], st[2 * p + 1]);

        // ---- layer 1: acc = [st, obs, act] @ W1 + b1   (f16x2 dot2) ----
        float acc[NH];
#pragma unroll
        for (int o = 0; o < NH; ++o) acc[o] = b1r[o];
#pragma unroll
        for (int p = 0; p < 5; ++p)
#pragma unroll
            for (int o = 0; o < NH; ++o) acc[o] = dot2(stp[p], w1p[p * NH + o], acc[o]);
#pragma unroll
        for (int p = 0; p < 10; ++p)
#pragma unroll
            for (int o = 0; o < NH; ++o) acc[o] = dot2(obsP[p], w1p[(5 + p) * NH + o], acc[o]);

        // obs consumed -> issue next step's loads (covered by rest of step)
        {
            const int sn = (s < NS - 1) ? s + 1 : s;
            const float* pf = row + sn * OBSD;
            nxt0 = *(const float4*)(pf + 0);
            nxt1 = *(const float4*)(pf + 4);
            nxt2 = *(const float4*)(pf + 8);
            nxt3 = *(const float4*)(pf + 12);
            nxt4 = *(const float4*)(pf + 16);
        }

#pragma unroll
        for (int o = 0; o < NH; ++o) acc[o] = dot2(actp, w1p[15 * NH + o], acc[o]);
#pragma unroll
        for (int o = 0; o < NH; ++o) acc[o] = ftanh(acc[o]);   // h1 in place

        // ---- layer 2: fp32, weights as SGPR operands ----
        float acc2[NH];
#pragma unroll
        for (int o = 0; o < NH; ++o) acc2[o] = b2r[o];
#pragma unroll
        for (int i = 0; i < NH; ++i) {
            const float xi = acc[i];
#pragma unroll
            for (int o = 0; o < NH; ++o) acc2[o] = fmaf(xi, w2l[i * NH + o], acc2[o]);
        }
#pragma unroll
        for (int o = 0; o < NH; ++o) acc2[o] = ftanh(acc2[o]); // h2 in place

        // ---- layer 3: st += h2 @ W3 + b3  (fp32, SGPR weights) ----
#pragma unroll
        for (int o = 0; o < NH; ++o) st[o] += b3r[o];
#pragma unroll
        for (int i = 0; i < NH; ++i) {
            const float xi = acc2[i];
#pragma unroll
            for (int o = 0; o < NH; ++o) st[o] = fmaf(xi, w3l[i * NH + o], st[o]);
        }
    }

    // ---- head: fp32, uniform weights ----
    float g[NH];
#pragma unroll
    for (int o = 0; o < NH; ++o) {
        float a = bg1[o];
#pragma unroll
        for (int i = 0; i < NH; ++i) a = fmaf(st[i], Wg1[i * NH + o], a);
        g[o] = ftanh(a);
    }
    float r = bg2[0];
#pragma unroll
    for (int o = 0; o < NH; ++o) r = fmaf(g[o], Wg2[o], r);
    out[b] = r;
}

extern "C" void kernel_launch(void* const* d_in, const int* in_sizes, int n_in,
                              void* d_out, int out_size, void* d_ws, size_t ws_size,
                              hipStream_t stream) {
    const float* states  = (const float*)d_in[0];
    const float* actions = (const float*)d_in[1];
    const float* W1  = (const float*)d_in[2];
    const float* b1  = (const float*)d_in[3];
    const float* W2  = (const float*)d_in[4];
    const float* b2  = (const float*)d_in[5];
    const float* W3  = (const float*)d_in[6];
    const float* b3  = (const float*)d_in[7];
    const float* Wg1 = (const float*)d_in[8];
    const float* bg1 = (const float*)d_in[9];
    const float* Wg2 = (const float*)d_in[10];
    const float* bg2 = (const float*)d_in[11];
    float* out = (float*)d_out;

    rd_fwd<<<NB / 256, 256, 0, stream>>>(states, actions, W1, b1, W2, b2,
                                         W3, b3, Wg1, bg1, Wg2, bg2, out);
}

// Round 5
// 100.349 us; speedup vs baseline: 5.4317x; 2.0312x over previous
//
#include <hip/hip_runtime.h>

// RecurrentDiscriminator round 5 (round-4 plan, compile fix):
// - W1 (15 pair-rows x 10) resident as f16x2 in ~150 arch VGPRs.
// - W2/W3 packed f16x2 resident in 100 AGPRs via explicit v_accvgpr_write,
//   read back per use with v_accvgpr_read (register move, no waitcnt).
// - Action contribution folded into step-invariant accInit (f32).
// - Only per-step memory: 5x global_load_dwordx4 obs prefetch, 1 step ahead.
// - Accumulators/state/tanh in f32; weights+activations f16 via v_dot2_f32_f16.

#define NB   65536
#define NS   64
#define OBSD 20
#define NH   10

// match __builtin_amdgcn_cvt_pkrtz's return type exactly
typedef __fp16 f16x2 __attribute__((ext_vector_type(2)));

#define KEEP(x) asm volatile("" : "+v"(x))

__device__ __forceinline__ float ftanh(float x) {
    // tanh(x) = 1 - 2/(exp(2x)+1); exact saturation at +/-inf
    float e = __builtin_amdgcn_exp2f(x * 2.885390081777927f);  // 2*log2(e)
    float r = __builtin_amdgcn_rcpf(1.0f + e);
    return fmaf(-2.0f, r, 1.0f);
}

__device__ __forceinline__ f16x2 pk(float a, float b) {
    return __builtin_amdgcn_cvt_pkrtz(a, b);
}

#if __has_builtin(__builtin_amdgcn_fdot2)
__device__ __forceinline__ float dot2(f16x2 a, f16x2 b, float c) {
    return __builtin_amdgcn_fdot2(a, b, c, false);
}
#else
__device__ __forceinline__ float dot2(f16x2 a, f16x2 b, float c) {
    return fmaf((float)a[0], (float)b[0], fmaf((float)a[1], (float)b[1], c));
}
#endif

// Deliberate AGPR parking: write once, read per use (1 VALU slot, no waitcnt).
__device__ __forceinline__ void agpr_put(float& slot, f16x2 v) {
    float f = __builtin_bit_cast(float, v);
    asm volatile("v_accvgpr_write_b32 %0, %1" : "=a"(slot) : "v"(f));
}
__device__ __forceinline__ f16x2 agpr_get(const float& slot) {
    float f;
    asm volatile("v_accvgpr_read_b32 %0, %1" : "=v"(f) : "a"(slot));
    return __builtin_bit_cast(f16x2, f);
}

__global__ __launch_bounds__(256, 1)
void rd_fwd(const float* __restrict__ states, const float* __restrict__ actions,
            const float* __restrict__ W1, const float* __restrict__ b1,
            const float* __restrict__ W2, const float* __restrict__ b2,
            const float* __restrict__ W3, const float* __restrict__ b3,
            const float* __restrict__ Wg1, const float* __restrict__ bg1,
            const float* __restrict__ Wg2, const float* __restrict__ bg2,
            float* __restrict__ out)
{
    const int b = blockIdx.x * blockDim.x + threadIdx.x;
    const float* __restrict__ row = states + (size_t)b * (NS * OBSD);

    // ---- W1 pair-rows 0..14 (state 0..4, obs 5..14) resident f16x2 ----
    f16x2 w1p[15 * NH];
#pragma unroll
    for (int p = 0; p < 15; ++p)
#pragma unroll
        for (int o = 0; o < NH; ++o)
            w1p[p * NH + o] = pk(W1[(2 * p) * NH + o], W1[(2 * p + 1) * NH + o]);
#pragma unroll
    for (int i = 0; i < 15 * NH; ++i) KEEP(w1p[i]);

    // ---- fold action rows + b1 into step-invariant accInit (f32, per-lane) ----
    const float a0 = actions[2 * b];
    const float a1 = actions[2 * b + 1];
    float accInit[NH];
#pragma unroll
    for (int o = 0; o < NH; ++o)
        accInit[o] = fmaf(a0, W1[30 * NH + o], fmaf(a1, W1[31 * NH + o], b1[o]));

    // ---- W2/W3 packed f16x2 into AGPRs ----
    float aw2[5 * NH], aw3[5 * NH];
#pragma unroll
    for (int p = 0; p < 5; ++p)
#pragma unroll
        for (int o = 0; o < NH; ++o) {
            agpr_put(aw2[p * NH + o], pk(W2[(2 * p) * NH + o], W2[(2 * p + 1) * NH + o]));
            agpr_put(aw3[p * NH + o], pk(W3[(2 * p) * NH + o], W3[(2 * p + 1) * NH + o]));
        }

    // biases b2/b3: wave-uniform -> SGPR-resident
    float b2r[NH], b3r[NH];
#pragma unroll
    for (int o = 0; o < NH; ++o) { b2r[o] = b2[o]; b3r[o] = b3[o]; }

    float st[NH];
#pragma unroll
    for (int o = 0; o < NH; ++o) st[o] = 0.0f;

    // obs prefetch for step 0
    float4 n0 = *(const float4*)(row + 0);
    float4 n1 = *(const float4*)(row + 4);
    float4 n2 = *(const float4*)(row + 8);
    float4 n3 = *(const float4*)(row + 12);
    float4 n4 = *(const float4*)(row + 16);

#pragma unroll 1
    for (int s = 0; s < NS; ++s) {
        // consume prefetched obs (vmcnt wait lands here), pack to f16x2
        f16x2 obsP[10];
        obsP[0] = pk(n0.x, n0.y); obsP[1] = pk(n0.z, n0.w);
        obsP[2] = pk(n1.x, n1.y); obsP[3] = pk(n1.z, n1.w);
        obsP[4] = pk(n2.x, n2.y); obsP[5] = pk(n2.z, n2.w);
        obsP[6] = pk(n3.x, n3.y); obsP[7] = pk(n3.z, n3.w);
        obsP[8] = pk(n4.x, n4.y); obsP[9] = pk(n4.z, n4.w);

        // immediately issue next step's loads (covered by this whole step)
        {
            const int sn = (s < NS - 1) ? s + 1 : s;
            const float* pf = row + sn * OBSD;
            n0 = *(const float4*)(pf + 0);
            n1 = *(const float4*)(pf + 4);
            n2 = *(const float4*)(pf + 8);
            n3 = *(const float4*)(pf + 12);
            n4 = *(const float4*)(pf + 16);
        }

        f16x2 stp[5];
#pragma unroll
        for (int p = 0; p < 5; ++p) stp[p] = pk(st[2 * p], st[2 * p + 1]);

        // ---- layer 1: acc = [st, obs] @ W1 + accInit ----
        float acc[NH];
#pragma unroll
        for (int o = 0; o < NH; ++o) acc[o] = accInit[o];
#pragma unroll
        for (int p = 0; p < 5; ++p)
#pragma unroll
            for (int o = 0; o < NH; ++o) acc[o] = dot2(stp[p], w1p[p * NH + o], acc[o]);
#pragma unroll
        for (int p = 0; p < 10; ++p)
#pragma unroll
            for (int o = 0; o < NH; ++o) acc[o] = dot2(obsP[p], w1p[(5 + p) * NH + o], acc[o]);
#pragma unroll
        for (int o = 0; o < NH; ++o) acc[o] = ftanh(acc[o]);   // h1 in place

        f16x2 h1p[5];
#pragma unroll
        for (int p = 0; p < 5; ++p) h1p[p] = pk(acc[2 * p], acc[2 * p + 1]);

        // ---- layer 2: acc2 = h1 @ W2 + b2  (weights from AGPR) ----
        float acc2[NH];
#pragma unroll
        for (int o = 0; o < NH; ++o) acc2[o] = b2r[o];
#pragma unroll
        for (int p = 0; p < 5; ++p)
#pragma unroll
            for (int o = 0; o < NH; ++o)
                acc2[o] = dot2(h1p[p], agpr_get(aw2[p * NH + o]), acc2[o]);
#pragma unroll
        for (int o = 0; o < NH; ++o) acc2[o] = ftanh(acc2[o]); // h2 in place

        f16x2 h2p[5];
#pragma unroll
        for (int p = 0; p < 5; ++p) h2p[p] = pk(acc2[2 * p], acc2[2 * p + 1]);

        // ---- layer 3: st += h2 @ W3 + b3  (weights from AGPR) ----
#pragma unroll
        for (int o = 0; o < NH; ++o) st[o] += b3r[o];
#pragma unroll
        for (int p = 0; p < 5; ++p)
#pragma unroll
            for (int o = 0; o < NH; ++o)
                st[o] = dot2(h2p[p], agpr_get(aw3[p * NH + o]), st[o]);
    }

    // ---- head (once, f32, uniform weights) ----
    float g[NH];
#pragma unroll
    for (int o = 0; o < NH; ++o) {
        float a = bg1[o];
#pragma unroll
        for (int i = 0; i < NH; ++i) a = fmaf(st[i], Wg1[i * NH + o], a);
        g[o] = ftanh(a);
    }
    float r = bg2[0];
#pragma unroll
    for (int o = 0; o < NH; ++o) r = fmaf(g[o], Wg2[o], r);
    out[b] = r;
}

extern "C" void kernel_launch(void* const* d_in, const int* in_sizes, int n_in,
                              void* d_out, int out_size, void* d_ws, size_t ws_size,
                              hipStream_t stream) {
    const float* states  = (const float*)d_in[0];
    const float* actions = (const float*)d_in[1];
    const float* W1  = (const float*)d_in[2];
    const float* b1  = (const float*)d_in[3];
    const float* W2  = (const float*)d_in[4];
    const float* b2  = (const float*)d_in[5];
    const float* W3  = (const float*)d_in[6];
    const float* b3  = (const float*)d_in[7];
    const float* Wg1 = (const float*)d_in[8];
    const float* bg1 = (const float*)d_in[9];
    const float* Wg2 = (const float*)d_in[10];
    const float* bg2 = (const float*)d_in[11];
    float* out = (float*)d_out;

    rd_fwd<<<NB / 256, 256, 0, stream>>>(states, actions, W1, b1, W2, b2,
                                         W3, b3, Wg1, bg1, Wg2, bg2, out);
}